// Round 9
// baseline (499.266 us; speedup 1.0000x reference)
//
#include <hip/hip_runtime.h>

// Problem constants
#define B_   8
#define SQ_  1024
#define SK_  1024
#define D_   512
#define H_   8
#define DFF_ 2048
#define L_   2
#define HD_  64
#define M_   8192   // B*SQ = B*SK rows

typedef __bf16 bf16;
using bf16x8 = __attribute__((ext_vector_type(8))) __bf16;
using f32x4  = __attribute__((ext_vector_type(4))) float;

__device__ inline f32x4 mfma16(bf16x8 a, bf16x8 b, f32x4 c) {
  return __builtin_amdgcn_mfma_f32_16x16x32_bf16(a, b, c, 0, 0, 0);
}

// async global->LDS DMA, 16B/lane; lane i lands at ldsbase + i*16 (m104/m108).
__device__ __forceinline__ void gl2lds16(const bf16* g, bf16* l) {
  __builtin_amdgcn_global_load_lds(
      (const __attribute__((address_space(1))) void*)g,
      (__attribute__((address_space(3))) void*)l, 16, 0, 0);
}

// fast GELU (tanh form): max |err| vs exact-erf GELU ~1e-3 -> negligible after
// Wf2 (std 0.02) propagation vs 0.105 output tolerance. 1 v_exp vs ~30-op erff.
__device__ __forceinline__ float gelu_fast(float x) {
  float u = 1.5957691216f * (x + 0.044715f * x * x * x);  // 2*0.7978845608
  return x / (1.0f + __expf(-u));  // 0.5x(1+tanh(u/2)) == x*sigmoid(u)
}

// ---------------------------------------------------------------------------
// Fused transpose+downcast for the four D x D weight stacks (WQ,WK,WV,WO).
// grid: (16, 16, 8)  z = weight*2 + layer. out[l][c][r] = (bf16)in[l][r][c]
// ---------------------------------------------------------------------------
struct TP4 { const float* in[4]; bf16* out[4]; };
__global__ __launch_bounds__(256) void transpose4_k(TP4 p) {
  __shared__ bf16 tile[32][33];
  int z = blockIdx.z, wsel = z >> 1, l = z & 1;
  const float* inp  = p.in[wsel]  + (size_t)l * D_ * D_;
  bf16*        outp = p.out[wsel] + (size_t)l * D_ * D_;
  int c0 = blockIdx.x * 32, r0 = blockIdx.y * 32;
  int tx = threadIdx.x & 31, ty = threadIdx.x >> 5;
#pragma unroll
  for (int i = 0; i < 32; i += 8)
    tile[ty + i][tx] = (bf16)inp[(size_t)(r0 + ty + i) * D_ + c0 + tx];
  __syncthreads();
#pragma unroll
  for (int i = 0; i < 32; i += 8)
    outp[(size_t)(c0 + ty + i) * D_ + r0 + tx] = tile[tx][ty + i];
}

// generic transpose+downcast (for Wf1/Wf2), grid (C/32, R/32, L)
__global__ __launch_bounds__(256) void transpose_k(
    const float* __restrict__ in, bf16* __restrict__ out, int R, int C) {
  __shared__ bf16 tile[32][33];
  const float* inp  = in  + (size_t)blockIdx.z * R * C;
  bf16*        outp = out + (size_t)blockIdx.z * R * C;
  int c0 = blockIdx.x * 32, r0 = blockIdx.y * 32;
  int tx = threadIdx.x & 31, ty = threadIdx.x >> 5;
#pragma unroll
  for (int i = 0; i < 32; i += 8)
    tile[ty + i][tx] = (bf16)inp[(size_t)(r0 + ty + i) * C + c0 + tx];
  __syncthreads();
#pragma unroll
  for (int i = 0; i < 32; i += 8)
    outp[(size_t)(c0 + ty + i) * R + r0 + tx] = tile[tx][ty + i];
}

// fused fp32->bf16 for q,k,v. grid: (M*D/1024, 3)
__global__ __launch_bounds__(256) void f2b3_k(
    const float* __restrict__ a, const float* __restrict__ b,
    const float* __restrict__ c, bf16* __restrict__ oa,
    bf16* __restrict__ ob, bf16* __restrict__ oc) {
  int which = blockIdx.y;
  const float* in = (which == 0) ? a : (which == 1) ? b : c;
  bf16* out = (which == 0) ? oa : (which == 1) ? ob : oc;
  int i = (blockIdx.x * 256 + threadIdx.x) * 4;
  float4 v = *(const float4*)&in[i];
  out[i] = (bf16)v.x; out[i + 1] = (bf16)v.y;
  out[i + 2] = (bf16)v.z; out[i + 3] = (bf16)v.w;
}

// ---------------------------------------------------------------------------
// 256x256 8-phase GEMM (T2+T3+T4+T5 stack) — verified r2..r8.
// ---------------------------------------------------------------------------
struct G256 { const bf16* A; const bf16* Bt; const float* bias; bf16* C; };

#define MFB(mh) \
  _Pragma("unroll") \
  for (int mi = 0; mi < 4; mi++) { \
    _Pragma("unroll") \
    for (int ni = 0; ni < 4; ni++) \
      acc[(mh) * 4 + mi][ni] = mfma16(a[mi], b[ni], acc[(mh) * 4 + mi][ni]); \
  }

#define PHASE(s, mh, STAGE, VM) \
  { \
    if ((mh) == 0) { \
      a[0] = ldA(s, 0); a[1] = ldA(s, 1); a[2] = ldA(s, 2); a[3] = ldA(s, 3); \
      b[0] = ldB(s, 0); b[1] = ldB(s, 1); b[2] = ldB(s, 2); b[3] = ldB(s, 3); \
    } else { \
      a[0] = ldA(s, 4); a[1] = ldA(s, 5); a[2] = ldA(s, 6); a[3] = ldA(s, 7); \
    } \
    STAGE; \
    VM; \
    __builtin_amdgcn_s_barrier(); \
    asm volatile("s_waitcnt lgkmcnt(0)" ::: "memory"); \
    __builtin_amdgcn_sched_barrier(0); \
    __builtin_amdgcn_s_setprio(1); \
    MFB(mh); \
    __builtin_amdgcn_s_setprio(0); \
    __builtin_amdgcn_s_barrier(); \
  }

__global__ __launch_bounds__(512, 2) void gemm256_k(G256 g0, G256 g1,
                                                    int Nsz, int Ksz,
                                                    int gelu) {
  __shared__ bf16 As[4 * 8192];   // 4 slots x [256 rows][32 k-elems]
  __shared__ bf16 Bs[4 * 8192];
  const G256 g = blockIdx.z ? g1 : g0;
  const int tid = threadIdx.x;
  const int w = tid >> 6, lane = tid & 63;
  const int quad = lane >> 4, l16 = lane & 15;
  const int wm = w >> 2, wn = w & 3;            // 2 x 4 wave grid
  const int m0 = blockIdx.x * 256, n0 = blockIdx.y * 256;
  const int NCH = Ksz >> 5;                     // 32-wide K-chunks
  const int ITERS = NCH >> 2;                   // 4 chunks / iteration

  const int srow = tid >> 2;                    // 0..127
  const int ssw = ((tid & 3) ^ (srow & 3) ^ ((srow >> 2) & 3)) << 3;
  const int swr = ((quad ^ (l16 & 3) ^ (l16 >> 2)) << 3);

  auto stageA = [&](int kc, int s) {
    const bf16* gp = g.A + (size_t)(m0 + srow) * Ksz + kc * 32 + ssw;
    gl2lds16(gp, &As[s * 8192 + w * 512]);
    gl2lds16(gp + (size_t)128 * Ksz, &As[s * 8192 + 4096 + w * 512]);
  };
  auto stageB = [&](int kc, int s) {
    const bf16* gp = g.Bt + (size_t)(n0 + srow) * Ksz + kc * 32 + ssw;
    gl2lds16(gp, &Bs[s * 8192 + w * 512]);
    gl2lds16(gp + (size_t)128 * Ksz, &Bs[s * 8192 + 4096 + w * 512]);
  };
  auto ldA = [&](int s, int mi) {
    return *(const bf16x8*)&As[s * 8192 + (wm * 128 + mi * 16 + l16) * 32 + swr];
  };
  auto ldB = [&](int s, int ni) {
    return *(const bf16x8*)&Bs[s * 8192 + (wn * 64 + ni * 16 + l16) * 32 + swr];
  };

  f32x4 acc[8][4] = {};

  stageA(0, 0); stageB(0, 0);
  stageA(1, 1); stageB(1, 1);
  stageA(2, 2); stageB(2, 2);
  asm volatile("s_waitcnt vmcnt(4)" ::: "memory");
  __builtin_amdgcn_s_barrier();

  for (int it = 0; it < ITERS; ++it) {
    const int c = it * 4;
    const bool last = (it + 1 == ITERS);
    bf16x8 a[4], b[4];
    PHASE(0, 0, stageA(c + 3, 3), )
    PHASE(0, 1, stageB(c + 3, 3), )
    PHASE(1, 0, if (!last) stageA(c + 4, 0), )
    PHASE(1, 1, if (!last) stageB(c + 4, 0),
          if (!last) { asm volatile("s_waitcnt vmcnt(4)" ::: "memory"); }
          else { asm volatile("s_waitcnt vmcnt(0)" ::: "memory"); })
    PHASE(2, 0, if (!last) stageA(c + 5, 1), )
    PHASE(2, 1, if (!last) stageB(c + 5, 1), )
    PHASE(3, 0, if (!last) stageA(c + 6, 2), )
    PHASE(3, 1, if (!last) stageB(c + 6, 2),
          asm volatile("s_waitcnt vmcnt(4)" ::: "memory"))
  }

#pragma unroll
  for (int mi = 0; mi < 8; mi++)
#pragma unroll
    for (int ni = 0; ni < 4; ni++) {
      const int col = n0 + wn * 64 + ni * 16 + l16;
      const float bv = g.bias[col];
#pragma unroll
      for (int r = 0; r < 4; r++) {
        const int row = m0 + wm * 128 + mi * 16 + quad * 4 + r;
        float x = acc[mi][ni][r] + bv;
        if (gelu) x = gelu_fast(x);
        g.C[(size_t)row * Nsz + col] = (bf16)x;
      }
    }
}

// ---------------------------------------------------------------------------
// Split-K clone of gemm256_k (schedule identical, epilogue differs).
// grid (M/256, N/256, KSPLIT). Part z covers K range [z*Kpart, (z+1)*Kpart).
// Writes bf16 PARTIAL (no bias, no gelu) to P + z*M*N. Verified r4..r8.
// ---------------------------------------------------------------------------
__global__ __launch_bounds__(512, 2) void gemm256s_k(
    const bf16* __restrict__ A, const bf16* __restrict__ Bt,
    bf16* __restrict__ P, int Nsz, int Kstride, int Kpart) {
  __shared__ bf16 As[4 * 8192];
  __shared__ bf16 Bs[4 * 8192];
  const int z = blockIdx.z;
  const int koff = z * Kpart;
  const int tid = threadIdx.x;
  const int w = tid >> 6, lane = tid & 63;
  const int quad = lane >> 4, l16 = lane & 15;
  const int wm = w >> 2, wn = w & 3;
  const int m0 = blockIdx.x * 256, n0 = blockIdx.y * 256;
  const int ITERS = (Kpart >> 5) >> 2;

  const int srow = tid >> 2;
  const int ssw = ((tid & 3) ^ (srow & 3) ^ ((srow >> 2) & 3)) << 3;
  const int swr = ((quad ^ (l16 & 3) ^ (l16 >> 2)) << 3);

  auto stageA = [&](int kc, int s) {
    const bf16* gp = A + (size_t)(m0 + srow) * Kstride + koff + kc * 32 + ssw;
    gl2lds16(gp, &As[s * 8192 + w * 512]);
    gl2lds16(gp + (size_t)128 * Kstride, &As[s * 8192 + 4096 + w * 512]);
  };
  auto stageB = [&](int kc, int s) {
    const bf16* gp = Bt + (size_t)(n0 + srow) * Kstride + koff + kc * 32 + ssw;
    gl2lds16(gp, &Bs[s * 8192 + w * 512]);
    gl2lds16(gp + (size_t)128 * Kstride, &Bs[s * 8192 + 4096 + w * 512]);
  };
  auto ldA = [&](int s, int mi) {
    return *(const bf16x8*)&As[s * 8192 + (wm * 128 + mi * 16 + l16) * 32 + swr];
  };
  auto ldB = [&](int s, int ni) {
    return *(const bf16x8*)&Bs[s * 8192 + (wn * 64 + ni * 16 + l16) * 32 + swr];
  };

  f32x4 acc[8][4] = {};

  stageA(0, 0); stageB(0, 0);
  stageA(1, 1); stageB(1, 1);
  stageA(2, 2); stageB(2, 2);
  asm volatile("s_waitcnt vmcnt(4)" ::: "memory");
  __builtin_amdgcn_s_barrier();

  for (int it = 0; it < ITERS; ++it) {
    const int c = it * 4;
    const bool last = (it + 1 == ITERS);
    bf16x8 a[4], b[4];
    PHASE(0, 0, stageA(c + 3, 3), )
    PHASE(0, 1, stageB(c + 3, 3), )
    PHASE(1, 0, if (!last) stageA(c + 4, 0), )
    PHASE(1, 1, if (!last) stageB(c + 4, 0),
          if (!last) { asm volatile("s_waitcnt vmcnt(4)" ::: "memory"); }
          else { asm volatile("s_waitcnt vmcnt(0)" ::: "memory"); })
    PHASE(2, 0, if (!last) stageA(c + 5, 1), )
    PHASE(2, 1, if (!last) stageB(c + 5, 1), )
    PHASE(3, 0, if (!last) stageA(c + 6, 2), )
    PHASE(3, 1, if (!last) stageB(c + 6, 2),
          asm volatile("s_waitcnt vmcnt(4)" ::: "memory"))
  }

  const size_t Msz = (size_t)gridDim.x * 256;
  bf16* Pz = P + (size_t)z * Msz * Nsz;
#pragma unroll
  for (int mi = 0; mi < 8; mi++)
#pragma unroll
    for (int ni = 0; ni < 4; ni++) {
      const int col = n0 + wn * 64 + ni * 16 + l16;
#pragma unroll
      for (int r = 0; r < 4; r++) {
        const int row = m0 + wm * 128 + mi * 16 + quad * 4 + r;
        Pz[(size_t)row * Nsz + col] = (bf16)acc[mi][ni][r];
      }
    }
}

// ---------------------------------------------------------------------------
// 128x128 8-phase GEMM for N=512 shapes (Qproj/Oproj) — r3-verified, kept.
// ---------------------------------------------------------------------------
__global__ __launch_bounds__(512, 2) void gemm128_k(
    const bf16* __restrict__ A, const bf16* __restrict__ Bt,
    const float* __restrict__ bias, bf16* __restrict__ Cb,
    float* __restrict__ Cf, int Nsz, int Ksz) {
  __shared__ bf16 As[4 * 4096];   // 4 slots x [128 rows][32 k]
  __shared__ bf16 Bs[4 * 4096];
  const int tid = threadIdx.x;
  const int w = tid >> 6, lane = tid & 63;
  const int quad = lane >> 4, l16 = lane & 15;
  const int wm = w >> 2, wn = w & 3;            // 2 x 4 wave grid
  const int m0 = blockIdx.x * 128, n0 = blockIdx.y * 128;
  const int NCH = Ksz >> 5;

  const int srow = tid >> 2;                    // 0..127
  const int ssw = ((tid & 3) ^ (srow & 3) ^ ((srow >> 2) & 3)) << 3;
  const int swr = ((quad ^ (l16 & 3) ^ (l16 >> 2)) << 3);

  auto stageChunk = [&](int kc) {
    const int s = kc & 3;
    gl2lds16(A + (size_t)(m0 + srow) * Ksz + kc * 32 + ssw,
             &As[s * 4096 + w * 512]);
    gl2lds16(Bt + (size_t)(n0 + srow) * Ksz + kc * 32 + ssw,
             &Bs[s * 4096 + w * 512]);
  };
  auto ldA = [&](int s, int mi) {
    return *(const bf16x8*)&As[s * 4096 + (wm * 64 + mi * 16 + l16) * 32 + swr];
  };
  auto ldB = [&](int s, int ni) {
    return *(const bf16x8*)&Bs[s * 4096 + (wn * 32 + ni * 16 + l16) * 32 + swr];
  };

  f32x4 acc[4][2] = {};

  stageChunk(0); stageChunk(1); stageChunk(2);
  asm volatile("s_waitcnt vmcnt(4)" ::: "memory");
  __builtin_amdgcn_s_barrier();

  auto phase = [&](int c, int vml) {
    const int s = c & 3;
    if (vml == 4) stageChunk(c + 3);
    bf16x8 a0 = ldA(s, 0), a1 = ldA(s, 1), a2 = ldA(s, 2), a3 = ldA(s, 3);
    bf16x8 b0 = ldB(s, 0), b1 = ldB(s, 1);
    if (vml == 4)      asm volatile("s_waitcnt vmcnt(4)" ::: "memory");
    else if (vml == 2) asm volatile("s_waitcnt vmcnt(2)" ::: "memory");
    else if (vml == 0) asm volatile("s_waitcnt vmcnt(0)" ::: "memory");
    __builtin_amdgcn_s_barrier();
    asm volatile("s_waitcnt lgkmcnt(0)" ::: "memory");
    __builtin_amdgcn_sched_barrier(0);
    __builtin_amdgcn_s_setprio(1);
    acc[0][0] = mfma16(a0, b0, acc[0][0]);
    acc[0][1] = mfma16(a0, b1, acc[0][1]);
    acc[1][0] = mfma16(a1, b0, acc[1][0]);
    acc[1][1] = mfma16(a1, b1, acc[1][1]);
    acc[2][0] = mfma16(a2, b0, acc[2][0]);
    acc[2][1] = mfma16(a2, b1, acc[2][1]);
    acc[3][0] = mfma16(a3, b0, acc[3][0]);
    acc[3][1] = mfma16(a3, b1, acc[3][1]);
    __builtin_amdgcn_s_setprio(0);
    __builtin_amdgcn_s_barrier();
  };

  for (int c = 0; c + 4 <= NCH; ++c) phase(c, 4);
  phase(NCH - 3, 2);
  phase(NCH - 2, 0);
  phase(NCH - 1, -1);

#pragma unroll
  for (int mi = 0; mi < 4; mi++)
#pragma unroll
    for (int ni = 0; ni < 2; ni++) {
      const int col = n0 + wn * 32 + ni * 16 + l16;
      const float bv = bias[col];
#pragma unroll
      for (int r = 0; r < 4; r++) {
        const int row = m0 + wm * 64 + mi * 16 + quad * 4 + r;
        float x = acc[mi][ni][r] + bv;
        size_t idx = (size_t)row * Nsz + col;
        if (Cb) Cb[idx] = (bf16)x;
        if (Cf) Cf[idx] = x;
      }
    }
}

// ---------------------------------------------------------------------------
// fused V^T builder for both layers. grid: (SK/64, B*H, 2)
// ---------------------------------------------------------------------------
__global__ __launch_bounds__(256) void vtrans2_k(const bf16* __restrict__ vhh,
                                                 bf16* __restrict__ vt0,
                                                 bf16* __restrict__ vt1) {
  __shared__ bf16 sm[64][72];
  int kt = blockIdx.x, bh = blockIdx.y, z = blockIdx.z;
  int coloff = z ? D_ : 0;
  bf16* vt = z ? vt1 : vt0;
  int b = bh >> 3, h = bh & 7;
  int tid = threadIdx.x;
  for (int c = tid; c < 512; c += 256) {
    int key = c >> 3, off = (c & 7) * 8;
    *(uint4*)&sm[key][off] = *(const uint4*)
        &vhh[(size_t)(b * SK_ + kt * 64 + key) * (2 * D_) + coloff + h * 64 + off];
  }
  __syncthreads();
  for (int c = tid; c < 512; c += 256) {
    int hd = c >> 3, koff = (c & 7) * 8;
    bf16 tmp[8];
#pragma unroll
    for (int j = 0; j < 8; j++) tmp[j] = sm[koff + j][hd];
    *(uint4*)&vt[(size_t)(bh * 64 + hd) * SK_ + kt * 64 + koff] = *(uint4*)tmp;
  }
}

// ---------------------------------------------------------------------------
// Flash attention, r9: T3+T4 applied — 4-slot LDS ring, counted vmcnt
// (never 0 in-loop), raw barriers. r8 diagnosis: per-tile the implicit
// vmcnt(0) drain in __syncthreads serialized the just-issued prefetch
// (~600cy/tile stall; FETCH fix r8 proved not memory-bound).
//   Ring: slot s = kt&3, prefetch depth 3. Per tile per wave U DMA ops
//   (U=3 HAS0, 2 else). vmcnt(3U) after stage(kt+3) -> slot kt complete;
//   tail 2U -> U -> 0 (kt=31's vmcnt(0) also drains before endpgm).
//   Overwrite safety: stage(kt+3) targets slot (kt-1)&3, whose reads ended
//   before the closing barrier of iter kt-1 (two raw barriers per tile).
//   LDS: HAS0 3x16KB + Ps 5KB = 53KB (3 blk/CU); else 37KB (4 blk/CU) —
//   r5 proved occupancy in this range isn't the binder.
//   Grid stays (bh, qt) XCD-local (r8: FETCH 106.6 -> 20.6 MB, kept).
// ---------------------------------------------------------------------------
template<bool HAS0>
__global__ __launch_bounds__(256) void attn_t(
    const bf16* __restrict__ qh, const bf16* __restrict__ qh0,
    const bf16* __restrict__ kh, const bf16* __restrict__ kh0, int kstride,
    const bf16* __restrict__ vt, const float* __restrict__ scale,
    const float* __restrict__ extra, int li, bf16* __restrict__ ctx) {
  __shared__ bf16 Ks[4 * 2048];                  // [slot][half d][32kv x 32d]
  __shared__ bf16 K0s[HAS0 ? 4 * 2048 : 64];
  __shared__ bf16 Vs[4 * 2048];                  // [slot][64hd x 32k]
  __shared__ bf16 Ps[4][16 * 40];                // per-wave, stride 40
  int qt = blockIdx.y, bh = blockIdx.x;          // XCD-local (r8)
  int b = bh >> 3, h = bh & 7;
  int tid = threadIdx.x, w = tid >> 6, lane = tid & 63;
  int quad = lane >> 4, l16 = lane & 15;
  const int rr = lane >> 2, c8 = (lane & 3) * 8;   // staging row/col-slot
  float eff1 = scale[li] * fminf(fmaxf(extra[li], 0.01f), 50.0f);
  float eff0 = HAS0 ? scale[li - 1] * fminf(fmaxf(extra[li - 1], 0.01f), 50.0f) : 0.f;

  bf16x8 aq[2], aq0[2];
  {
    int qrow = b * SQ_ + qt * 64 + w * 16 + l16;
    const bf16* qp = qh + (size_t)qrow * D_ + h * 64 + quad * 8;
    aq[0] = *(const bf16x8*)qp; aq[1] = *(const bf16x8*)(qp + 32);
#pragma unroll
    for (int k2 = 0; k2 < 2; k2++)
#pragma unroll
      for (int j = 0; j < 8; j++)
        aq[k2][j] = (bf16)((float)aq[k2][j] * eff1);
    if constexpr (HAS0) {
      const bf16* qp0 = qh0 + (size_t)qrow * D_ + h * 64 + quad * 8;
      aq0[0] = *(const bf16x8*)qp0; aq0[1] = *(const bf16x8*)(qp0 + 32);
#pragma unroll
      for (int k2 = 0; k2 < 2; k2++)
#pragma unroll
        for (int j = 0; j < 8; j++)
          aq0[k2][j] = (bf16)((float)aq0[k2][j] * eff0);
    }
  }
  bf16x8 ones;
#pragma unroll
  for (int j = 0; j < 8; j++) ones[j] = (bf16)1.0f;

  f32x4 o[4] = {};
  f32x4 ol = {};

  // staging: unit u covers 16 rows x 32 cols (1KB). HAS0: u 0-3 K, 4-7 K0,
  // 8-11 V. else: 0-3 K, 4-7 V. Wave w does u = w + 4*ui. (r5-verbatim,
  // slot-indexed)
  auto stage = [&](int kt, int s) {
#pragma unroll
    for (int ui = 0; ui < (HAS0 ? 3 : 2); ui++) {
      int u = w + ui * 4;
      if (u < 4) {
        int hf = u >> 1, g = u & 1;
        gl2lds16(&kh[(size_t)(b * SK_ + kt * 32 + g * 16 + rr) * kstride +
                     h * 64 + hf * 32 + c8],
                 &Ks[s * 2048 + hf * 1024 + g * 512]);
      } else if (HAS0 && u < 8) {
        int uu = u - 4; int hf = uu >> 1, g = uu & 1;
        gl2lds16(&kh0[(size_t)(b * SK_ + kt * 32 + g * 16 + rr) * kstride +
                      h * 64 + hf * 32 + c8],
                 &K0s[s * 2048 + hf * 1024 + g * 512]);
      } else {
        int g2 = u & 3;
        gl2lds16(&vt[(size_t)(bh * 64 + g2 * 16 + rr) * SK_ + kt * 32 + c8],
                 &Vs[s * 2048 + g2 * 512]);
      }
    }
  };

  // counted vmcnt (branches fold to literals at each call site)
  auto vmwait = [&](int n) {
    if (n >= 9)      asm volatile("s_waitcnt vmcnt(9)" ::: "memory");
    else if (n == 6) asm volatile("s_waitcnt vmcnt(6)" ::: "memory");
    else if (n == 4) asm volatile("s_waitcnt vmcnt(4)" ::: "memory");
    else if (n == 3) asm volatile("s_waitcnt vmcnt(3)" ::: "memory");
    else if (n == 2) asm volatile("s_waitcnt vmcnt(2)" ::: "memory");
    else             asm volatile("s_waitcnt vmcnt(0)" ::: "memory");
  };
  const int U = HAS0 ? 3 : 2;

  // prologue: tiles 0,1,2 -> slots 0,1,2 (3U ops in flight)
  stage(0, 0); stage(1, 1); stage(2, 2);

  for (int kt = 0; kt < SK_ / 32; kt++) {
    const int s = kt & 3;
    if (kt + 3 < SK_ / 32) stage(kt + 3, (kt + 3) & 3);
    const int out = (SK_ / 32 - 1 - kt < 3) ? (SK_ / 32 - 1 - kt) : 3;
    vmwait(out * U);                   // slot kt complete (mine)
    __builtin_amdgcn_s_barrier();      // everyone's slot kt complete
#pragma unroll
    for (int ni = 0; ni < 2; ni++) {
      int ro = (ni * 16 + l16) * 32 + quad * 8;
      f32x4 t = {};
      t = mfma16(aq[0], *(const bf16x8*)&Ks[s * 2048 + ro], t);
      t = mfma16(aq[1], *(const bf16x8*)&Ks[s * 2048 + 1024 + ro], t);
      if constexpr (HAS0) {
        t = mfma16(aq0[0], *(const bf16x8*)&K0s[s * 2048 + ro], t);
        t = mfma16(aq0[1], *(const bf16x8*)&K0s[s * 2048 + 1024 + ro], t);
      }
#pragma unroll
      for (int r = 0; r < 4; r++)
        Ps[w][(quad * 4 + r) * 40 + ni * 16 + l16] = (bf16)__expf(t[r]);
    }
    {
      bf16x8 ap = *(const bf16x8*)&Ps[w][l16 * 40 + quad * 8];
      ol = mfma16(ap, ones, ol);
#pragma unroll
      for (int ni = 0; ni < 4; ni++)
        o[ni] = mfma16(ap,
                       *(const bf16x8*)&Vs[s * 2048 + (ni * 16 + l16) * 32 +
                                           quad * 8],
                       o[ni]);
    }
    __builtin_amdgcn_s_barrier();      // reads of slot kt done -> slot
                                       // reusable by stage(kt+4) next iter
  }
#pragma unroll
  for (int ni = 0; ni < 4; ni++)
#pragma unroll
    for (int r = 0; r < 4; r++) {
      int row = b * SQ_ + qt * 64 + w * 16 + quad * 4 + r;
      ctx[(size_t)row * D_ + h * 64 + ni * 16 + l16] =
          (bf16)(o[ni][r] / ol[r]);
    }
}

// ---------------------------------------------------------------------------
// Gated residual + post-LN  (attn side, unchanged)
// ---------------------------------------------------------------------------
__global__ __launch_bounds__(256) void ln_k(
    const float* __restrict__ cur_in, const float* __restrict__ add,
    const float* __restrict__ gate, const float* __restrict__ g,
    const float* __restrict__ bb, float* __restrict__ outf,
    bf16* __restrict__ outb) {
  int row = blockIdx.x, tid = threadIdx.x;
  float gv = gate[0];
  float sp = gv > 20.f ? gv : log1pf(expf(gv));
  size_t base = (size_t)row * D_;
  int c0 = tid * 2;
  float2 c2 = *(const float2*)&cur_in[base + c0];
  float2 a2 = *(const float2*)&add[base + c0];
  float x0 = c2.x + sp * a2.x, x1 = c2.y + sp * a2.y;
  float s = x0 + x1, s2 = x0 * x0 + x1 * x1;
#pragma unroll
  for (int m = 1; m < 64; m <<= 1) {
    s += __shfl_xor(s, m);
    s2 += __shfl_xor(s2, m);
  }
  __shared__ float sa[4], sb[4];
  int w = tid >> 6;
  if ((tid & 63) == 0) { sa[w] = s; sb[w] = s2; }
  __syncthreads();
  s = sa[0] + sa[1] + sa[2] + sa[3];
  s2 = sb[0] + sb[1] + sb[2] + sb[3];
  float mu = s * (1.f / D_);
  float var = s2 * (1.f / D_) - mu * mu;
  float rs = rsqrtf(var + 1e-5f);
  float y0 = (x0 - mu) * rs * g[c0] + bb[c0];
  float y1 = (x1 - mu) * rs * g[c0 + 1] + bb[c0 + 1];
  if (outf) { float2 y; y.x = y0; y.y = y1; *(float2*)&outf[base + c0] = y; }
  if (outb) { outb[base + c0] = (bf16)y0; outb[base + c0 + 1] = (bf16)y1; }
}

// ---------------------------------------------------------------------------
// FFN-side LN: sums 4 bf16 split-K partials + bias, then gated residual + LN.
// ---------------------------------------------------------------------------
__global__ __launch_bounds__(256) void ln4_k(
    const float* __restrict__ cur_in, const bf16* __restrict__ P,
    const float* __restrict__ bias2, const float* __restrict__ gate,
    const float* __restrict__ g, const float* __restrict__ bb,
    float* __restrict__ outf, bf16* __restrict__ outb) {
  int row = blockIdx.x, tid = threadIdx.x;
  float gv = gate[0];
  float sp = gv > 20.f ? gv : log1pf(expf(gv));
  size_t base = (size_t)row * D_;
  int c0 = tid * 2;
  float2 c2 = *(const float2*)&cur_in[base + c0];
  float a0 = bias2[c0], a1 = bias2[c0 + 1];
  const size_t MD = (size_t)M_ * D_;
#pragma unroll
  for (int z = 0; z < 4; z++) {
    const bf16* pp = P + z * MD + base + c0;
    a0 += (float)pp[0];
    a1 += (float)pp[1];
  }
  float x0 = c2.x + sp * a0, x1 = c2.y + sp * a1;
  float s = x0 + x1, s2 = x0 * x0 + x1 * x1;
#pragma unroll
  for (int m = 1; m < 64; m <<= 1) {
    s += __shfl_xor(s, m);
    s2 += __shfl_xor(s2, m);
  }
  __shared__ float sa[4], sb[4];
  int w = tid >> 6;
  if ((tid & 63) == 0) { sa[w] = s; sb[w] = s2; }
  __syncthreads();
  s = sa[0] + sa[1] + sa[2] + sa[3];
  s2 = sb[0] + sb[1] + sb[2] + sb[3];
  float mu = s * (1.f / D_);
  float var = s2 * (1.f / D_) - mu * mu;
  float rs = rsqrtf(var + 1e-5f);
  float y0 = (x0 - mu) * rs * g[c0] + bb[c0];
  float y1 = (x1 - mu) * rs * g[c0 + 1] + bb[c0 + 1];
  if (outf) { float2 y; y.x = y0; y.y = y1; *(float2*)&outf[base + c0] = y; }
  if (outb) { outb[base + c0] = (bf16)y0; outb[base + c0 + 1] = (bf16)y1; }
}

// ---------------------------------------------------------------------------
extern "C" void kernel_launch(void* const* d_in, const int* in_sizes, int n_in,
                              void* d_out, int out_size, void* d_ws,
                              size_t ws_size, hipStream_t stream) {
  const float* qin = (const float*)d_in[0];
  const float* kin = (const float*)d_in[1];
  const float* vin = (const float*)d_in[2];
  const float* WQ  = (const float*)d_in[3];
  const float* bQ  = (const float*)d_in[4];
  const float* WK  = (const float*)d_in[5];
  const float* bK  = (const float*)d_in[6];
  const float* WV  = (const float*)d_in[7];
  const float* bV  = (const float*)d_in[8];
  const float* WO  = (const float*)d_in[9];
  const float* bO  = (const float*)d_in[10];
  const float* Wf1 = (const float*)d_in[11];
  const float* bf1 = (const float*)d_in[12];
  const float* Wf2 = (const float*)d_in[13];
  const float* bf2 = (const float*)d_in[14];
  const float* l1g = (const float*)d_in[15];
  const float* l1b = (const float*)d_in[16];
  const float* l2g = (const float*)d_in[17];
  const float* l2b = (const float*)d_in[18];
  const float* sc  = (const float*)d_in[19];
  const float* ex  = (const float*)d_in[20];
  const float* ga  = (const float*)d_in[21];
  const float* gf  = (const float*)d_in[22];

  char* p = (char*)d_ws;
  auto alloc = [&](size_t bytes) {
    void* r = (void*)p;
    p += (bytes + 255) & ~(size_t)255;
    return r;
  };
  bf16* WQt  = (bf16*)alloc((size_t)L_ * D_ * D_ * 2);
  bf16* WKt  = (bf16*)alloc((size_t)L_ * D_ * D_ * 2);
  bf16* WVt  = (bf16*)alloc((size_t)L_ * D_ * D_ * 2);
  bf16* WOt  = (bf16*)alloc((size_t)L_ * D_ * D_ * 2);
  bf16* Wf1t = (bf16*)alloc((size_t)L_ * D_ * DFF_ * 2);
  bf16* Wf2t = (bf16*)alloc((size_t)L_ * D_ * DFF_ * 2);
  float* cur  = (float*)alloc((size_t)M_ * D_ * 4);
  bf16* curb  = (bf16*)alloc((size_t)M_ * D_ * 2);
  bf16* qb    = (bf16*)alloc((size_t)M_ * D_ * 2);
  bf16* kb    = (bf16*)alloc((size_t)M_ * D_ * 2);
  bf16* vb    = (bf16*)alloc((size_t)M_ * D_ * 2);
  bf16* khh   = (bf16*)alloc((size_t)M_ * 2 * D_ * 2);  // both layers
  bf16* vhh   = (bf16*)alloc((size_t)M_ * 2 * D_ * 2);
  bf16* qh0b  = (bf16*)alloc((size_t)M_ * D_ * 2);
  bf16* qh1b  = (bf16*)alloc((size_t)M_ * D_ * 2);
  bf16* vt0   = (bf16*)alloc((size_t)M_ * D_ * 2);
  bf16* vt1   = (bf16*)alloc((size_t)M_ * D_ * 2);
  bf16* ctx   = (bf16*)alloc((size_t)M_ * D_ * 2);
  // proj (16MB) + ffout (16MB) contiguous: doubles as 4 x 8MB bf16 split-K
  // partial region for FFN2 (live ranges disjoint).
  float* proj  = (float*)alloc((size_t)M_ * D_ * 4);
  float* ffout = (float*)alloc((size_t)M_ * D_ * 4);
  bf16* parts  = (bf16*)proj;                           // 4 x M*D bf16
  bf16* ffmid  = (bf16*)alloc((size_t)M_ * DFF_ * 2);
  (void)ffout;

  // prep (fused)
  TP4 tp; tp.in[0] = WQ; tp.in[1] = WK; tp.in[2] = WV; tp.in[3] = WO;
  tp.out[0] = WQt; tp.out[1] = WKt; tp.out[2] = WVt; tp.out[3] = WOt;
  transpose4_k<<<dim3(16, 16, 8), 256, 0, stream>>>(tp);
  transpose_k<<<dim3(DFF_ / 32, D_ / 32, L_), 256, 0, stream>>>(Wf1, Wf1t, D_, DFF_);
  transpose_k<<<dim3(D_ / 32, DFF_ / 32, L_), 256, 0, stream>>>(Wf2, Wf2t, DFF_, D_);
  f2b3_k<<<dim3((M_ * D_) / 1024, 3), 256, 0, stream>>>(qin, kin, vin, qb, kb, vb);

  // hoisted: K/V projections for BOTH layers, batched into ONE 256-block
  // launch (32 x 4 x 2 = 256 = 1 block/CU).
  G256 gk; gk.A = kb; gk.Bt = WKt; gk.bias = bK; gk.C = khh;
  G256 gvv; gvv.A = vb; gvv.Bt = WVt; gvv.bias = bV; gvv.C = vhh;
  gemm256_k<<<dim3(M_ / 256, (2 * D_) / 256, 2), 512, 0, stream>>>(
      gk, gvv, 2 * D_, D_, 0);
  vtrans2_k<<<dim3(SK_ / 64, B_ * H_, 2), 256, 0, stream>>>(vhh, vt0, vt1);
  // layer-0 Q projection: 128^2 8-phase, grid 64 x 4 = 256 blocks.
  gemm128_k<<<dim3(M_ / 128, 4), 512, 0, stream>>>(
      qb, WQt, bQ, qh0b, nullptr, D_, D_);

  for (int li = 0; li < L_; li++) {
    if (li > 0)
      gemm128_k<<<dim3(M_ / 128, 4), 512, 0, stream>>>(
          curb, WQt + (size_t)li * D_ * D_, bQ + li * D_, qh1b, nullptr, D_, D_);
    if (li == 0)
      attn_t<false><<<dim3(B_ * H_, SQ_ / 64), 256, 0, stream>>>(
          qh0b, qh0b, khh, khh, 2 * D_, vt0, sc, ex, 0, ctx);
    else
      attn_t<true><<<dim3(B_ * H_, SQ_ / 64), 256, 0, stream>>>(
          qh1b, qh0b, khh + (size_t)li * D_, khh, 2 * D_, vt1, sc, ex, 1, ctx);
    gemm128_k<<<dim3(M_ / 128, 4), 512, 0, stream>>>(
        ctx, WOt + (size_t)li * D_ * D_, bO + li * D_, nullptr, proj, D_, D_);
    ln_k<<<M_, 256, 0, stream>>>((li == 0) ? qin : cur, proj, ga + li,
                                 l1g + li * D_, l1b + li * D_, cur, curb);
    // FFN1 on the 8-phase 256^2 kernel: grid 32 x 8 = 256 = 1 block/CU.
    G256 gf1; gf1.A = curb; gf1.Bt = Wf1t + (size_t)li * D_ * DFF_;
    gf1.bias = bf1 + li * DFF_; gf1.C = ffmid;
    gemm256_k<<<dim3(M_ / 256, DFF_ / 256, 1), 512, 0, stream>>>(
        gf1, gf1, DFF_, D_, 1);
    // FFN2 (K=2048) split-K=4 on the verified 256^2 schedule.
    gemm256s_k<<<dim3(M_ / 256, D_ / 256, 4), 512, 0, stream>>>(
        ffmid, Wf2t + (size_t)li * DFF_ * D_, parts, D_, DFF_, DFF_ / 4);
    ln4_k<<<M_, 256, 0, stream>>>(cur, parts, bf2 + li * D_, gf + li,
                                  l2g + li * D_, l2b + li * D_,
                                  (li == L_ - 1) ? (float*)d_out : cur,
                                  (li == L_ - 1) ? nullptr : curb);
  }
}

// Round 10
// 489.110 us; speedup vs baseline: 1.0208x; 1.0208x over previous
//
#include <hip/hip_runtime.h>

// Problem constants
#define B_   8
#define SQ_  1024
#define SK_  1024
#define D_   512
#define H_   8
#define DFF_ 2048
#define L_   2
#define HD_  64
#define M_   8192   // B*SQ = B*SK rows

typedef __bf16 bf16;
using bf16x8 = __attribute__((ext_vector_type(8))) __bf16;
using f32x4  = __attribute__((ext_vector_type(4))) float;

__device__ inline f32x4 mfma16(bf16x8 a, bf16x8 b, f32x4 c) {
  return __builtin_amdgcn_mfma_f32_16x16x32_bf16(a, b, c, 0, 0, 0);
}

// async global->LDS DMA, 16B/lane; lane i lands at ldsbase + i*16 (m104/m108).
__device__ __forceinline__ void gl2lds16(const bf16* g, bf16* l) {
  __builtin_amdgcn_global_load_lds(
      (const __attribute__((address_space(1))) void*)g,
      (__attribute__((address_space(3))) void*)l, 16, 0, 0);
}

// fast GELU (tanh form): max |err| vs exact-erf GELU ~1e-3 -> negligible after
// Wf2 (std 0.02) propagation vs 0.105 output tolerance. 1 v_exp vs ~30-op erff.
__device__ __forceinline__ float gelu_fast(float x) {
  float u = 1.5957691216f * (x + 0.044715f * x * x * x);  // 2*0.7978845608
  return x / (1.0f + __expf(-u));  // 0.5x(1+tanh(u/2)) == x*sigmoid(u)
}

// ---------------------------------------------------------------------------
// Fused prep (r10): ONE launch replacing transpose4_k + 2x transpose_k +
// f2b3_k (removes 3 graph-node gaps; independent pieces overlap).
// 1-D grid 18432 blocks x 256:
//   [0,2048)      transpose4: z=id>>8 (wsel=z>>1, l=z&1), 32x32 tile of DxD
//   [2048,4096)   Wf1^T: R=D, C=DFF, grid (64,16,2) linearized
//   [4096,6144)   Wf2^T: R=DFF, C=D, grid (16,64,2) linearized
//   [6144,18432)  f2b3: 4096 blocks per tensor (q,k,v), float4->bf16x4
// ---------------------------------------------------------------------------
struct PrepA {
  const float* w4i[4]; bf16* w4o[4];
  const float* wf1; bf16* wf1t;
  const float* wf2; bf16* wf2t;
  const float* q; const float* k; const float* v;
  bf16* qb; bf16* kb; bf16* vb;
};
__global__ __launch_bounds__(256) void prep_k(PrepA p) {
  __shared__ bf16 tile[32][33];
  const int id = blockIdx.x, tid = threadIdx.x;
  const int tx = tid & 31, ty = tid >> 5;
  if (id < 2048) {
    int z = id >> 8, wsel = z >> 1, l = z & 1;
    int r = id & 255;
    int c0 = (r & 15) * 32, r0 = (r >> 4) * 32;
    const float* inp = p.w4i[wsel] + (size_t)l * D_ * D_;
    bf16* outp = p.w4o[wsel] + (size_t)l * D_ * D_;
#pragma unroll
    for (int i = 0; i < 32; i += 8)
      tile[ty + i][tx] = (bf16)inp[(size_t)(r0 + ty + i) * D_ + c0 + tx];
    __syncthreads();
#pragma unroll
    for (int i = 0; i < 32; i += 8)
      outp[(size_t)(c0 + ty + i) * D_ + r0 + tx] = tile[tx][ty + i];
  } else if (id < 4096) {
    int idx = id - 2048; int l = idx >> 10; idx &= 1023;
    int c0 = (idx & 63) * 32, r0 = (idx >> 6) * 32;   // C=DFF, R=D
    const float* inp = p.wf1 + (size_t)l * D_ * DFF_;
    bf16* outp = p.wf1t + (size_t)l * D_ * DFF_;
#pragma unroll
    for (int i = 0; i < 32; i += 8)
      tile[ty + i][tx] = (bf16)inp[(size_t)(r0 + ty + i) * DFF_ + c0 + tx];
    __syncthreads();
#pragma unroll
    for (int i = 0; i < 32; i += 8)
      outp[(size_t)(c0 + ty + i) * D_ + r0 + tx] = tile[tx][ty + i];
  } else if (id < 6144) {
    int idx = id - 4096; int l = idx >> 10; idx &= 1023;
    int c0 = (idx & 15) * 32, r0 = (idx >> 4) * 32;   // C=D, R=DFF
    const float* inp = p.wf2 + (size_t)l * DFF_ * D_;
    bf16* outp = p.wf2t + (size_t)l * DFF_ * D_;
#pragma unroll
    for (int i = 0; i < 32; i += 8)
      tile[ty + i][tx] = (bf16)inp[(size_t)(r0 + ty + i) * D_ + c0 + tx];
    __syncthreads();
#pragma unroll
    for (int i = 0; i < 32; i += 8)
      outp[(size_t)(c0 + ty + i) * DFF_ + r0 + tx] = tile[tx][ty + i];
  } else {
    int idx = id - 6144;
    int which = idx >> 12, bx = idx & 4095;
    const float* in = (which == 0) ? p.q : (which == 1) ? p.k : p.v;
    bf16* out = (which == 0) ? p.qb : (which == 1) ? p.kb : p.vb;
    int i = (bx * 256 + tid) * 4;
    float4 v = *(const float4*)&in[i];
    out[i] = (bf16)v.x; out[i + 1] = (bf16)v.y;
    out[i + 2] = (bf16)v.z; out[i + 3] = (bf16)v.w;
  }
}

// ---------------------------------------------------------------------------
// 256x256 8-phase GEMM (T2+T3+T4+T5 stack) — verified r2..r9.
// ---------------------------------------------------------------------------
struct G256 { const bf16* A; const bf16* Bt; const float* bias; bf16* C; };

#define MFB(mh) \
  _Pragma("unroll") \
  for (int mi = 0; mi < 4; mi++) { \
    _Pragma("unroll") \
    for (int ni = 0; ni < 4; ni++) \
      acc[(mh) * 4 + mi][ni] = mfma16(a[mi], b[ni], acc[(mh) * 4 + mi][ni]); \
  }

#define PHASE(s, mh, STAGE, VM) \
  { \
    if ((mh) == 0) { \
      a[0] = ldA(s, 0); a[1] = ldA(s, 1); a[2] = ldA(s, 2); a[3] = ldA(s, 3); \
      b[0] = ldB(s, 0); b[1] = ldB(s, 1); b[2] = ldB(s, 2); b[3] = ldB(s, 3); \
    } else { \
      a[0] = ldA(s, 4); a[1] = ldA(s, 5); a[2] = ldA(s, 6); a[3] = ldA(s, 7); \
    } \
    STAGE; \
    VM; \
    __builtin_amdgcn_s_barrier(); \
    asm volatile("s_waitcnt lgkmcnt(0)" ::: "memory"); \
    __builtin_amdgcn_sched_barrier(0); \
    __builtin_amdgcn_s_setprio(1); \
    MFB(mh); \
    __builtin_amdgcn_s_setprio(0); \
    __builtin_amdgcn_s_barrier(); \
  }

__global__ __launch_bounds__(512, 2) void gemm256_k(G256 g0, G256 g1,
                                                    int Nsz, int Ksz,
                                                    int gelu) {
  __shared__ bf16 As[4 * 8192];   // 4 slots x [256 rows][32 k-elems]
  __shared__ bf16 Bs[4 * 8192];
  const G256 g = blockIdx.z ? g1 : g0;
  const int tid = threadIdx.x;
  const int w = tid >> 6, lane = tid & 63;
  const int quad = lane >> 4, l16 = lane & 15;
  const int wm = w >> 2, wn = w & 3;            // 2 x 4 wave grid
  const int m0 = blockIdx.x * 256, n0 = blockIdx.y * 256;
  const int NCH = Ksz >> 5;                     // 32-wide K-chunks
  const int ITERS = NCH >> 2;                   // 4 chunks / iteration

  const int srow = tid >> 2;                    // 0..127
  const int ssw = ((tid & 3) ^ (srow & 3) ^ ((srow >> 2) & 3)) << 3;
  const int swr = ((quad ^ (l16 & 3) ^ (l16 >> 2)) << 3);

  auto stageA = [&](int kc, int s) {
    const bf16* gp = g.A + (size_t)(m0 + srow) * Ksz + kc * 32 + ssw;
    gl2lds16(gp, &As[s * 8192 + w * 512]);
    gl2lds16(gp + (size_t)128 * Ksz, &As[s * 8192 + 4096 + w * 512]);
  };
  auto stageB = [&](int kc, int s) {
    const bf16* gp = g.Bt + (size_t)(n0 + srow) * Ksz + kc * 32 + ssw;
    gl2lds16(gp, &Bs[s * 8192 + w * 512]);
    gl2lds16(gp + (size_t)128 * Ksz, &Bs[s * 8192 + 4096 + w * 512]);
  };
  auto ldA = [&](int s, int mi) {
    return *(const bf16x8*)&As[s * 8192 + (wm * 128 + mi * 16 + l16) * 32 + swr];
  };
  auto ldB = [&](int s, int ni) {
    return *(const bf16x8*)&Bs[s * 8192 + (wn * 64 + ni * 16 + l16) * 32 + swr];
  };

  f32x4 acc[8][4] = {};

  stageA(0, 0); stageB(0, 0);
  stageA(1, 1); stageB(1, 1);
  stageA(2, 2); stageB(2, 2);
  asm volatile("s_waitcnt vmcnt(4)" ::: "memory");
  __builtin_amdgcn_s_barrier();

  for (int it = 0; it < ITERS; ++it) {
    const int c = it * 4;
    const bool last = (it + 1 == ITERS);
    bf16x8 a[4], b[4];
    PHASE(0, 0, stageA(c + 3, 3), )
    PHASE(0, 1, stageB(c + 3, 3), )
    PHASE(1, 0, if (!last) stageA(c + 4, 0), )
    PHASE(1, 1, if (!last) stageB(c + 4, 0),
          if (!last) { asm volatile("s_waitcnt vmcnt(4)" ::: "memory"); }
          else { asm volatile("s_waitcnt vmcnt(0)" ::: "memory"); })
    PHASE(2, 0, if (!last) stageA(c + 5, 1), )
    PHASE(2, 1, if (!last) stageB(c + 5, 1), )
    PHASE(3, 0, if (!last) stageA(c + 6, 2), )
    PHASE(3, 1, if (!last) stageB(c + 6, 2),
          asm volatile("s_waitcnt vmcnt(4)" ::: "memory"))
  }

#pragma unroll
  for (int mi = 0; mi < 8; mi++)
#pragma unroll
    for (int ni = 0; ni < 4; ni++) {
      const int col = n0 + wn * 64 + ni * 16 + l16;
      const float bv = g.bias[col];
#pragma unroll
      for (int r = 0; r < 4; r++) {
        const int row = m0 + wm * 128 + mi * 16 + quad * 4 + r;
        float x = acc[mi][ni][r] + bv;
        if (gelu) x = gelu_fast(x);
        g.C[(size_t)row * Nsz + col] = (bf16)x;
      }
    }
}

// ---------------------------------------------------------------------------
// Split-K clone of gemm256_k (schedule identical, epilogue differs).
// grid (M/256, N/256, KSPLIT). Part z covers K range [z*Kpart, (z+1)*Kpart).
// Writes bf16 PARTIAL (no bias, no gelu) to P + z*M*N. Verified r4..r9.
// ---------------------------------------------------------------------------
__global__ __launch_bounds__(512, 2) void gemm256s_k(
    const bf16* __restrict__ A, const bf16* __restrict__ Bt,
    bf16* __restrict__ P, int Nsz, int Kstride, int Kpart) {
  __shared__ bf16 As[4 * 8192];
  __shared__ bf16 Bs[4 * 8192];
  const int z = blockIdx.z;
  const int koff = z * Kpart;
  const int tid = threadIdx.x;
  const int w = tid >> 6, lane = tid & 63;
  const int quad = lane >> 4, l16 = lane & 15;
  const int wm = w >> 2, wn = w & 3;
  const int m0 = blockIdx.x * 256, n0 = blockIdx.y * 256;
  const int ITERS = (Kpart >> 5) >> 2;

  const int srow = tid >> 2;
  const int ssw = ((tid & 3) ^ (srow & 3) ^ ((srow >> 2) & 3)) << 3;
  const int swr = ((quad ^ (l16 & 3) ^ (l16 >> 2)) << 3);

  auto stageA = [&](int kc, int s) {
    const bf16* gp = A + (size_t)(m0 + srow) * Kstride + koff + kc * 32 + ssw;
    gl2lds16(gp, &As[s * 8192 + w * 512]);
    gl2lds16(gp + (size_t)128 * Kstride, &As[s * 8192 + 4096 + w * 512]);
  };
  auto stageB = [&](int kc, int s) {
    const bf16* gp = Bt + (size_t)(n0 + srow) * Kstride + koff + kc * 32 + ssw;
    gl2lds16(gp, &Bs[s * 8192 + w * 512]);
    gl2lds16(gp + (size_t)128 * Kstride, &Bs[s * 8192 + 4096 + w * 512]);
  };
  auto ldA = [&](int s, int mi) {
    return *(const bf16x8*)&As[s * 8192 + (wm * 128 + mi * 16 + l16) * 32 + swr];
  };
  auto ldB = [&](int s, int ni) {
    return *(const bf16x8*)&Bs[s * 8192 + (wn * 64 + ni * 16 + l16) * 32 + swr];
  };

  f32x4 acc[8][4] = {};

  stageA(0, 0); stageB(0, 0);
  stageA(1, 1); stageB(1, 1);
  stageA(2, 2); stageB(2, 2);
  asm volatile("s_waitcnt vmcnt(4)" ::: "memory");
  __builtin_amdgcn_s_barrier();

  for (int it = 0; it < ITERS; ++it) {
    const int c = it * 4;
    const bool last = (it + 1 == ITERS);
    bf16x8 a[4], b[4];
    PHASE(0, 0, stageA(c + 3, 3), )
    PHASE(0, 1, stageB(c + 3, 3), )
    PHASE(1, 0, if (!last) stageA(c + 4, 0), )
    PHASE(1, 1, if (!last) stageB(c + 4, 0),
          if (!last) { asm volatile("s_waitcnt vmcnt(4)" ::: "memory"); }
          else { asm volatile("s_waitcnt vmcnt(0)" ::: "memory"); })
    PHASE(2, 0, if (!last) stageA(c + 5, 1), )
    PHASE(2, 1, if (!last) stageB(c + 5, 1), )
    PHASE(3, 0, if (!last) stageA(c + 6, 2), )
    PHASE(3, 1, if (!last) stageB(c + 6, 2),
          asm volatile("s_waitcnt vmcnt(4)" ::: "memory"))
  }

  const size_t Msz = (size_t)gridDim.x * 256;
  bf16* Pz = P + (size_t)z * Msz * Nsz;
#pragma unroll
  for (int mi = 0; mi < 8; mi++)
#pragma unroll
    for (int ni = 0; ni < 4; ni++) {
      const int col = n0 + wn * 64 + ni * 16 + l16;
#pragma unroll
      for (int r = 0; r < 4; r++) {
        const int row = m0 + wm * 128 + mi * 16 + quad * 4 + r;
        Pz[(size_t)row * Nsz + col] = (bf16)acc[mi][ni][r];
      }
    }
}

// ---------------------------------------------------------------------------
// 128x128 8-phase GEMM for N=512 shapes (Qproj/Oproj) — r3-verified, kept.
// ---------------------------------------------------------------------------
__global__ __launch_bounds__(512, 2) void gemm128_k(
    const bf16* __restrict__ A, const bf16* __restrict__ Bt,
    const float* __restrict__ bias, bf16* __restrict__ Cb,
    float* __restrict__ Cf, int Nsz, int Ksz) {
  __shared__ bf16 As[4 * 4096];   // 4 slots x [128 rows][32 k]
  __shared__ bf16 Bs[4 * 4096];
  const int tid = threadIdx.x;
  const int w = tid >> 6, lane = tid & 63;
  const int quad = lane >> 4, l16 = lane & 15;
  const int wm = w >> 2, wn = w & 3;            // 2 x 4 wave grid
  const int m0 = blockIdx.x * 128, n0 = blockIdx.y * 128;
  const int NCH = Ksz >> 5;

  const int srow = tid >> 2;                    // 0..127
  const int ssw = ((tid & 3) ^ (srow & 3) ^ ((srow >> 2) & 3)) << 3;
  const int swr = ((quad ^ (l16 & 3) ^ (l16 >> 2)) << 3);

  auto stageChunk = [&](int kc) {
    const int s = kc & 3;
    gl2lds16(A + (size_t)(m0 + srow) * Ksz + kc * 32 + ssw,
             &As[s * 4096 + w * 512]);
    gl2lds16(Bt + (size_t)(n0 + srow) * Ksz + kc * 32 + ssw,
             &Bs[s * 4096 + w * 512]);
  };
  auto ldA = [&](int s, int mi) {
    return *(const bf16x8*)&As[s * 4096 + (wm * 64 + mi * 16 + l16) * 32 + swr];
  };
  auto ldB = [&](int s, int ni) {
    return *(const bf16x8*)&Bs[s * 4096 + (wn * 32 + ni * 16 + l16) * 32 + swr];
  };

  f32x4 acc[4][2] = {};

  stageChunk(0); stageChunk(1); stageChunk(2);
  asm volatile("s_waitcnt vmcnt(4)" ::: "memory");
  __builtin_amdgcn_s_barrier();

  auto phase = [&](int c, int vml) {
    const int s = c & 3;
    if (vml == 4) stageChunk(c + 3);
    bf16x8 a0 = ldA(s, 0), a1 = ldA(s, 1), a2 = ldA(s, 2), a3 = ldA(s, 3);
    bf16x8 b0 = ldB(s, 0), b1 = ldB(s, 1);
    if (vml == 4)      asm volatile("s_waitcnt vmcnt(4)" ::: "memory");
    else if (vml == 2) asm volatile("s_waitcnt vmcnt(2)" ::: "memory");
    else if (vml == 0) asm volatile("s_waitcnt vmcnt(0)" ::: "memory");
    __builtin_amdgcn_s_barrier();
    asm volatile("s_waitcnt lgkmcnt(0)" ::: "memory");
    __builtin_amdgcn_sched_barrier(0);
    __builtin_amdgcn_s_setprio(1);
    acc[0][0] = mfma16(a0, b0, acc[0][0]);
    acc[0][1] = mfma16(a0, b1, acc[0][1]);
    acc[1][0] = mfma16(a1, b0, acc[1][0]);
    acc[1][1] = mfma16(a1, b1, acc[1][1]);
    acc[2][0] = mfma16(a2, b0, acc[2][0]);
    acc[2][1] = mfma16(a2, b1, acc[2][1]);
    acc[3][0] = mfma16(a3, b0, acc[3][0]);
    acc[3][1] = mfma16(a3, b1, acc[3][1]);
    __builtin_amdgcn_s_setprio(0);
    __builtin_amdgcn_s_barrier();
  };

  for (int c = 0; c + 4 <= NCH; ++c) phase(c, 4);
  phase(NCH - 3, 2);
  phase(NCH - 2, 0);
  phase(NCH - 1, -1);

#pragma unroll
  for (int mi = 0; mi < 4; mi++)
#pragma unroll
    for (int ni = 0; ni < 2; ni++) {
      const int col = n0 + wn * 32 + ni * 16 + l16;
      const float bv = bias[col];
#pragma unroll
      for (int r = 0; r < 4; r++) {
        const int row = m0 + wm * 64 + mi * 16 + quad * 4 + r;
        float x = acc[mi][ni][r] + bv;
        size_t idx = (size_t)row * Nsz + col;
        if (Cb) Cb[idx] = (bf16)x;
        if (Cf) Cf[idx] = x;
      }
    }
}

// ---------------------------------------------------------------------------
// fused V^T builder for both layers. grid: (SK/64, B*H, 2)
// ---------------------------------------------------------------------------
__global__ __launch_bounds__(256) void vtrans2_k(const bf16* __restrict__ vhh,
                                                 bf16* __restrict__ vt0,
                                                 bf16* __restrict__ vt1) {
  __shared__ bf16 sm[64][72];
  int kt = blockIdx.x, bh = blockIdx.y, z = blockIdx.z;
  int coloff = z ? D_ : 0;
  bf16* vt = z ? vt1 : vt0;
  int b = bh >> 3, h = bh & 7;
  int tid = threadIdx.x;
  for (int c = tid; c < 512; c += 256) {
    int key = c >> 3, off = (c & 7) * 8;
    *(uint4*)&sm[key][off] = *(const uint4*)
        &vhh[(size_t)(b * SK_ + kt * 64 + key) * (2 * D_) + coloff + h * 64 + off];
  }
  __syncthreads();
  for (int c = tid; c < 512; c += 256) {
    int hd = c >> 3, koff = (c & 7) * 8;
    bf16 tmp[8];
#pragma unroll
    for (int j = 0; j < 8; j++) tmp[j] = sm[koff + j][hd];
    *(uint4*)&vt[(size_t)(bh * 64 + hd) * SK_ + kt * 64 + koff] = *(uint4*)tmp;
  }
}

// ---------------------------------------------------------------------------
// Flash attention, r10 = r8-exact (best verified: 56.8us, occ 33%).
// r9's T3/T4 ring REVERTED (LDS 54KB -> occ 20%, 63.3us). Attn verdict after
// six levers (occupancy/HBM/conflict/T15/T3T4/direct-global): glued at
// ~56.5us by the serial QK->exp->Ps->PV chain under block barriers.
// Grid (bh, qt): XCD-local KV (r8: FETCH 106.6 -> 20.6 MB).
// ---------------------------------------------------------------------------
template<bool HAS0>
__global__ __launch_bounds__(256) void attn_t(
    const bf16* __restrict__ qh, const bf16* __restrict__ qh0,
    const bf16* __restrict__ kh, const bf16* __restrict__ kh0, int kstride,
    const bf16* __restrict__ vt, const float* __restrict__ scale,
    const float* __restrict__ extra, int li, bf16* __restrict__ ctx) {
  __shared__ bf16 Ks[2 * 2048];                  // [buf][half d][32kv x 32d]
  __shared__ bf16 K0s[HAS0 ? 2 * 2048 : 64];
  __shared__ bf16 Vs[2 * 2048];                  // [buf][64hd x 32k]
  __shared__ bf16 Ps[4][16 * 40];                // per-wave, stride 40
  int qt = blockIdx.y, bh = blockIdx.x;          // XCD-local (r8)
  int b = bh >> 3, h = bh & 7;
  int tid = threadIdx.x, w = tid >> 6, lane = tid & 63;
  int quad = lane >> 4, l16 = lane & 15;
  const int rr = lane >> 2, c8 = (lane & 3) * 8;   // staging row/col-slot
  float eff1 = scale[li] * fminf(fmaxf(extra[li], 0.01f), 50.0f);
  float eff0 = HAS0 ? scale[li - 1] * fminf(fmaxf(extra[li - 1], 0.01f), 50.0f) : 0.f;

  bf16x8 aq[2], aq0[2];
  {
    int qrow = b * SQ_ + qt * 64 + w * 16 + l16;
    const bf16* qp = qh + (size_t)qrow * D_ + h * 64 + quad * 8;
    aq[0] = *(const bf16x8*)qp; aq[1] = *(const bf16x8*)(qp + 32);
#pragma unroll
    for (int k2 = 0; k2 < 2; k2++)
#pragma unroll
      for (int j = 0; j < 8; j++)
        aq[k2][j] = (bf16)((float)aq[k2][j] * eff1);
    if constexpr (HAS0) {
      const bf16* qp0 = qh0 + (size_t)qrow * D_ + h * 64 + quad * 8;
      aq0[0] = *(const bf16x8*)qp0; aq0[1] = *(const bf16x8*)(qp0 + 32);
#pragma unroll
      for (int k2 = 0; k2 < 2; k2++)
#pragma unroll
        for (int j = 0; j < 8; j++)
          aq0[k2][j] = (bf16)((float)aq0[k2][j] * eff0);
    }
  }
  bf16x8 ones;
#pragma unroll
  for (int j = 0; j < 8; j++) ones[j] = (bf16)1.0f;

  f32x4 o[4] = {};
  f32x4 ol = {};

  // staging: unit u covers 16 rows x 32 cols (1KB). HAS0: u 0-3 K, 4-7 K0,
  // 8-11 V. else: 0-3 K, 4-7 V. Wave w does u = w + 4*ui.  (r5-verbatim)
  auto stage = [&](int kt, int bufi) {
#pragma unroll
    for (int ui = 0; ui < (HAS0 ? 3 : 2); ui++) {
      int u = w + ui * 4;
      if (u < 4) {
        int hf = u >> 1, g = u & 1;
        gl2lds16(&kh[(size_t)(b * SK_ + kt * 32 + g * 16 + rr) * kstride +
                     h * 64 + hf * 32 + c8],
                 &Ks[bufi * 2048 + hf * 1024 + g * 512]);
      } else if (HAS0 && u < 8) {
        int uu = u - 4; int hf = uu >> 1, g = uu & 1;
        gl2lds16(&kh0[(size_t)(b * SK_ + kt * 32 + g * 16 + rr) * kstride +
                      h * 64 + hf * 32 + c8],
                 &K0s[bufi * 2048 + hf * 1024 + g * 512]);
      } else {
        int g2 = u & 3;
        gl2lds16(&vt[(size_t)(bh * 64 + g2 * 16 + rr) * SK_ + kt * 32 + c8],
                 &Vs[bufi * 2048 + g2 * 512]);
      }
    }
  };

  stage(0, 0);
  __syncthreads();
  int buf = 0;
  for (int kt = 0; kt < SK_ / 32; kt++, buf ^= 1) {
    if (kt + 1 < SK_ / 32) stage(kt + 1, buf ^ 1);
#pragma unroll
    for (int ni = 0; ni < 2; ni++) {
      int ro = (ni * 16 + l16) * 32 + quad * 8;
      f32x4 t = {};
      t = mfma16(aq[0], *(const bf16x8*)&Ks[buf * 2048 + ro], t);
      t = mfma16(aq[1], *(const bf16x8*)&Ks[buf * 2048 + 1024 + ro], t);
      if constexpr (HAS0) {
        t = mfma16(aq0[0], *(const bf16x8*)&K0s[buf * 2048 + ro], t);
        t = mfma16(aq0[1], *(const bf16x8*)&K0s[buf * 2048 + 1024 + ro], t);
      }
#pragma unroll
      for (int r = 0; r < 4; r++)
        Ps[w][(quad * 4 + r) * 40 + ni * 16 + l16] = (bf16)__expf(t[r]);
    }
    {
      bf16x8 ap = *(const bf16x8*)&Ps[w][l16 * 40 + quad * 8];
      ol = mfma16(ap, ones, ol);
#pragma unroll
      for (int ni = 0; ni < 4; ni++)
        o[ni] = mfma16(ap,
                       *(const bf16x8*)&Vs[buf * 2048 + (ni * 16 + l16) * 32 +
                                           quad * 8],
                       o[ni]);
    }
    __syncthreads();
  }
#pragma unroll
  for (int ni = 0; ni < 4; ni++)
#pragma unroll
    for (int r = 0; r < 4; r++) {
      int row = b * SQ_ + qt * 64 + w * 16 + quad * 4 + r;
      ctx[(size_t)row * D_ + h * 64 + ni * 16 + l16] =
          (bf16)(o[ni][r] / ol[r]);
    }
}

// ---------------------------------------------------------------------------
// Gated residual + post-LN (attn side). r10: addend is bf16 (O-proj writes
// bf16 into the parts region) — halves add-stream HBM traffic; bf16 rounding
// of the pre-LN addend ~0.4% rel., within 0.031->0.105 margin.
// ---------------------------------------------------------------------------
__global__ __launch_bounds__(256) void ln_k(
    const float* __restrict__ cur_in, const bf16* __restrict__ add,
    const float* __restrict__ gate, const float* __restrict__ g,
    const float* __restrict__ bb, float* __restrict__ outf,
    bf16* __restrict__ outb) {
  int row = blockIdx.x, tid = threadIdx.x;
  float gv = gate[0];
  float sp = gv > 20.f ? gv : log1pf(expf(gv));
  size_t base = (size_t)row * D_;
  int c0 = tid * 2;
  float2 c2 = *(const float2*)&cur_in[base + c0];
  const bf16* ap = add + base + c0;
  float x0 = c2.x + sp * (float)ap[0], x1 = c2.y + sp * (float)ap[1];
  float s = x0 + x1, s2 = x0 * x0 + x1 * x1;
#pragma unroll
  for (int m = 1; m < 64; m <<= 1) {
    s += __shfl_xor(s, m);
    s2 += __shfl_xor(s2, m);
  }
  __shared__ float sa[4], sb[4];
  int w = tid >> 6;
  if ((tid & 63) == 0) { sa[w] = s; sb[w] = s2; }
  __syncthreads();
  s = sa[0] + sa[1] + sa[2] + sa[3];
  s2 = sb[0] + sb[1] + sb[2] + sb[3];
  float mu = s * (1.f / D_);
  float var = s2 * (1.f / D_) - mu * mu;
  float rs = rsqrtf(var + 1e-5f);
  float y0 = (x0 - mu) * rs * g[c0] + bb[c0];
  float y1 = (x1 - mu) * rs * g[c0 + 1] + bb[c0 + 1];
  if (outf) { float2 y; y.x = y0; y.y = y1; *(float2*)&outf[base + c0] = y; }
  if (outb) { outb[base + c0] = (bf16)y0; outb[base + c0 + 1] = (bf16)y1; }
}

// ---------------------------------------------------------------------------
// FFN-side LN: sums 4 bf16 split-K partials + bias, then gated residual + LN.
// ---------------------------------------------------------------------------
__global__ __launch_bounds__(256) void ln4_k(
    const float* __restrict__ cur_in, const bf16* __restrict__ P,
    const float* __restrict__ bias2, const float* __restrict__ gate,
    const float* __restrict__ g, const float* __restrict__ bb,
    float* __restrict__ outf, bf16* __restrict__ outb) {
  int row = blockIdx.x, tid = threadIdx.x;
  float gv = gate[0];
  float sp = gv > 20.f ? gv : log1pf(expf(gv));
  size_t base = (size_t)row * D_;
  int c0 = tid * 2;
  float2 c2 = *(const float2*)&cur_in[base + c0];
  float a0 = bias2[c0], a1 = bias2[c0 + 1];
  const size_t MD = (size_t)M_ * D_;
#pragma unroll
  for (int z = 0; z < 4; z++) {
    const bf16* pp = P + z * MD + base + c0;
    a0 += (float)pp[0];
    a1 += (float)pp[1];
  }
  float x0 = c2.x + sp * a0, x1 = c2.y + sp * a1;
  float s = x0 + x1, s2 = x0 * x0 + x1 * x1;
#pragma unroll
  for (int m = 1; m < 64; m <<= 1) {
    s += __shfl_xor(s, m);
    s2 += __shfl_xor(s2, m);
  }
  __shared__ float sa[4], sb[4];
  int w = tid >> 6;
  if ((tid & 63) == 0) { sa[w] = s; sb[w] = s2; }
  __syncthreads();
  s = sa[0] + sa[1] + sa[2] + sa[3];
  s2 = sb[0] + sb[1] + sb[2] + sb[3];
  float mu = s * (1.f / D_);
  float var = s2 * (1.f / D_) - mu * mu;
  float rs = rsqrtf(var + 1e-5f);
  float y0 = (x0 - mu) * rs * g[c0] + bb[c0];
  float y1 = (x1 - mu) * rs * g[c0 + 1] + bb[c0 + 1];
  if (outf) { float2 y; y.x = y0; y.y = y1; *(float2*)&outf[base + c0] = y; }
  if (outb) { outb[base + c0] = (bf16)y0; outb[base + c0 + 1] = (bf16)y1; }
}

// ---------------------------------------------------------------------------
extern "C" void kernel_launch(void* const* d_in, const int* in_sizes, int n_in,
                              void* d_out, int out_size, void* d_ws,
                              size_t ws_size, hipStream_t stream) {
  const float* qin = (const float*)d_in[0];
  const float* kin = (const float*)d_in[1];
  const float* vin = (const float*)d_in[2];
  const float* WQ  = (const float*)d_in[3];
  const float* bQ  = (const float*)d_in[4];
  const float* WK  = (const float*)d_in[5];
  const float* bK  = (const float*)d_in[6];
  const float* WV  = (const float*)d_in[7];
  const float* bV  = (const float*)d_in[8];
  const float* WO  = (const float*)d_in[9];
  const float* bO  = (const float*)d_in[10];
  const float* Wf1 = (const float*)d_in[11];
  const float* bf1 = (const float*)d_in[12];
  const float* Wf2 = (const float*)d_in[13];
  const float* bf2 = (const float*)d_in[14];
  const float* l1g = (const float*)d_in[15];
  const float* l1b = (const float*)d_in[16];
  const float* l2g = (const float*)d_in[17];
  const float* l2b = (const float*)d_in[18];
  const float* sc  = (const float*)d_in[19];
  const float* ex  = (const float*)d_in[20];
  const float* ga  = (const float*)d_in[21];
  const float* gf  = (const float*)d_in[22];

  char* p = (char*)d_ws;
  auto alloc = [&](size_t bytes) {
    void* r = (void*)p;
    p += (bytes + 255) & ~(size_t)255;
    return r;
  };
  bf16* WQt  = (bf16*)alloc((size_t)L_ * D_ * D_ * 2);
  bf16* WKt  = (bf16*)alloc((size_t)L_ * D_ * D_ * 2);
  bf16* WVt  = (bf16*)alloc((size_t)L_ * D_ * D_ * 2);
  bf16* WOt  = (bf16*)alloc((size_t)L_ * D_ * D_ * 2);
  bf16* Wf1t = (bf16*)alloc((size_t)L_ * D_ * DFF_ * 2);
  bf16* Wf2t = (bf16*)alloc((size_t)L_ * D_ * DFF_ * 2);
  float* cur  = (float*)alloc((size_t)M_ * D_ * 4);
  bf16* curb  = (bf16*)alloc((size_t)M_ * D_ * 2);
  bf16* qb    = (bf16*)alloc((size_t)M_ * D_ * 2);
  bf16* kb    = (bf16*)alloc((size_t)M_ * D_ * 2);
  bf16* vb    = (bf16*)alloc((size_t)M_ * D_ * 2);
  bf16* khh   = (bf16*)alloc((size_t)M_ * 2 * D_ * 2);  // both layers
  bf16* vhh   = (bf16*)alloc((size_t)M_ * 2 * D_ * 2);
  bf16* qh0b  = (bf16*)alloc((size_t)M_ * D_ * 2);
  bf16* qh1b  = (bf16*)alloc((size_t)M_ * D_ * 2);
  bf16* vt0   = (bf16*)alloc((size_t)M_ * D_ * 2);
  bf16* vt1   = (bf16*)alloc((size_t)M_ * D_ * 2);
  bf16* ctx   = (bf16*)alloc((size_t)M_ * D_ * 2);
  // proj (16MB) + ffout (16MB) contiguous: doubles as 4 x 8MB bf16 split-K
  // partial region for FFN2 AND as the bf16 O-proj output (live ranges
  // disjoint: projb live Oproj->ln1; parts live gemm256s->ln4).
  float* proj  = (float*)alloc((size_t)M_ * D_ * 4);
  float* ffout = (float*)alloc((size_t)M_ * D_ * 4);
  bf16* parts  = (bf16*)proj;                           // 4 x M*D bf16
  bf16* projb  = (bf16*)proj;                           // M*D bf16 (O-proj)
  bf16* ffmid  = (bf16*)alloc((size_t)M_ * DFF_ * 2);
  (void)ffout;

  // fused prep: transposes + downcasts in ONE launch
  PrepA pa;
  pa.w4i[0] = WQ; pa.w4i[1] = WK; pa.w4i[2] = WV; pa.w4i[3] = WO;
  pa.w4o[0] = WQt; pa.w4o[1] = WKt; pa.w4o[2] = WVt; pa.w4o[3] = WOt;
  pa.wf1 = Wf1; pa.wf1t = Wf1t; pa.wf2 = Wf2; pa.wf2t = Wf2t;
  pa.q = qin; pa.k = kin; pa.v = vin; pa.qb = qb; pa.kb = kb; pa.vb = vb;
  prep_k<<<18432, 256, 0, stream>>>(pa);

  // hoisted: K/V projections for BOTH layers, batched into ONE 256-block
  // launch (32 x 4 x 2 = 256 = 1 block/CU).
  G256 gk; gk.A = kb; gk.Bt = WKt; gk.bias = bK; gk.C = khh;
  G256 gvv; gvv.A = vb; gvv.Bt = WVt; gvv.bias = bV; gvv.C = vhh;
  gemm256_k<<<dim3(M_ / 256, (2 * D_) / 256, 2), 512, 0, stream>>>(
      gk, gvv, 2 * D_, D_, 0);
  vtrans2_k<<<dim3(SK_ / 64, B_ * H_, 2), 256, 0, stream>>>(vhh, vt0, vt1);
  // layer-0 Q projection: 128^2 8-phase, grid 64 x 4 = 256 blocks.
  gemm128_k<<<dim3(M_ / 128, 4), 512, 0, stream>>>(
      qb, WQt, bQ, qh0b, nullptr, D_, D_);

  for (int li = 0; li < L_; li++) {
    if (li > 0)
      gemm128_k<<<dim3(M_ / 128, 4), 512, 0, stream>>>(
          curb, WQt + (size_t)li * D_ * D_, bQ + li * D_, qh1b, nullptr, D_, D_);
    if (li == 0)
      attn_t<false><<<dim3(B_ * H_, SQ_ / 64), 256, 0, stream>>>(
          qh0b, qh0b, khh, khh, 2 * D_, vt0, sc, ex, 0, ctx);
    else
      attn_t<true><<<dim3(B_ * H_, SQ_ / 64), 256, 0, stream>>>(
          qh1b, qh0b, khh + (size_t)li * D_, khh, 2 * D_, vt1, sc, ex, 1, ctx);
    // O-proj -> bf16 (projb aliases parts region; dead before FFN2 partials)
    gemm128_k<<<dim3(M_ / 128, 4), 512, 0, stream>>>(
        ctx, WOt + (size_t)li * D_ * D_, bO + li * D_, projb, nullptr, D_, D_);
    ln_k<<<M_, 256, 0, stream>>>((li == 0) ? qin : cur, projb, ga + li,
                                 l1g + li * D_, l1b + li * D_, cur, curb);
    // FFN1 on the 8-phase 256^2 kernel: grid 32 x 8 = 256 = 1 block/CU.
    G256 gf1; gf1.A = curb; gf1.Bt = Wf1t + (size_t)li * D_ * DFF_;
    gf1.bias = bf1 + li * DFF_; gf1.C = ffmid;
    gemm256_k<<<dim3(M_ / 256, DFF_ / 256, 1), 512, 0, stream>>>(
        gf1, gf1, DFF_, D_, 1);
    // FFN2 (K=2048) split-K=4 on the verified 256^2 schedule.
    gemm256s_k<<<dim3(M_ / 256, D_ / 256, 4), 512, 0, stream>>>(
        ffmid, Wf2t + (size_t)li * DFF_ * D_, parts, D_, DFF_, DFF_ / 4);
    ln4_k<<<M_, 256, 0, stream>>>(cur, parts, bf2 + li * D_, gf + li,
                                  l2g + li * D_, l2b + li * D_,
                                  (li == L_ - 1) ? (float*)d_out : cur,
                                  (li == L_ - 1) ? nullptr : curb);
  }
}